// Round 12
// baseline (1811.852 us; speedup 1.0000x reference)
//
#include <hip/hip_runtime.h>
#include <hip/hip_bf16.h>

// ---- problem constants ----
#define NW 5
#define KS 5
#define SEQ 196
#define DIM 384
#define NSUP 25        // NW*KS support images
#define NQRY 75        // query images
#define NIMG 100       // NSUP + NQRY
#define LSUP 4900      // NSUP*SEQ support rows
#define LSUP_PAD 4992  // 39*128, zero-padded K rows
#define QROWS 208      // padded qs rows per image (13*16)
#define BLOCK_W 980    // KS*SEQ rows per class block
#define OPT_STEPS 15
#define MTILES 39      // LSUP_PAD / MT
#define NSUPWG (NSUP * MTILES)   // 975 support GEMM blocks
#define NQWG   (NQRY * MTILES)   // 2925 query GEMM blocks
#define SPIN_LIMIT (1u << 22)    // hang-proofing

static constexpr float TEMP_F = 0.0510310363f;
static constexpr float INV_T  = 1.0f / TEMP_F;   // ~19.5959
static constexpr float LR_F   = 0.1f;

typedef short v8s __attribute__((ext_vector_type(8)));   // 8 x bf16 frag (4 VGPRs)
typedef float v4f __attribute__((ext_vector_type(4)));   // 4 x f32 acc

__device__ inline unsigned short f2bf(float x) {
    unsigned int u = __float_as_uint(x);
    u += 0x7fffu + ((u >> 16) & 1u);
    return (unsigned short)(u >> 16);
}

__device__ __forceinline__ unsigned fresh_u32(unsigned* p) {
    return __hip_atomic_fetch_add(p, 0u, __ATOMIC_RELAXED, __HIP_MEMORY_SCOPE_AGENT);
}
__device__ __forceinline__ void agent_store_u32(unsigned* p, unsigned v) {
    __hip_atomic_store(p, v, __ATOMIC_RELAXED, __HIP_MEMORY_SCOPE_AGENT);
}

// ---------------------------------------------------------------------------
// Kernel 1: fused normalize. Wave-per-row.
// ---------------------------------------------------------------------------
__global__ __launch_bounds__(256) void norm_all(const float* __restrict__ supk,
                                                const float* __restrict__ supq,
                                                const float* __restrict__ qry,
                                                unsigned short* __restrict__ Kb,
                                                unsigned short* __restrict__ Qall) {
    int R = blockIdx.x * 4 + (threadIdx.x >> 6);
    int l = threadIdx.x & 63;
    unsigned short* out;
    const float* in;
    float scale;
    if (R < LSUP_PAD) {
        out = Kb + (size_t)R * DIM;
        if (R >= LSUP) {
            #pragma unroll
            for (int k = 0; k < 6; ++k) out[l + 64 * k] = 0;
            return;
        }
        in = supk + (size_t)R * DIM;
        scale = INV_T;
    } else {
        int i = R - LSUP_PAD;
        int img = i / QROWS;
        int r = i - img * QROWS;
        out = Qall + (size_t)i * DIM;
        if (r >= SEQ) {
            #pragma unroll
            for (int k = 0; k < 6; ++k) out[l + 64 * k] = 0;
            return;
        }
        in = (img < NSUP)
            ? supq + ((size_t)img * SEQ + r) * DIM
            : qry  + ((size_t)(img - NSUP) * SEQ + r) * DIM;
        scale = 1.0f;
    }
    float x[6];
    #pragma unroll
    for (int k = 0; k < 6; ++k) x[k] = in[l + 64 * k];
    float s = 0.f;
    #pragma unroll
    for (int k = 0; k < 6; ++k) s += x[k] * x[k];
    #pragma unroll
    for (int m = 1; m < 64; m <<= 1) s += __shfl_xor(s, m);
    float sc = scale / fmaxf(sqrtf(s), 1e-8f);
    #pragma unroll
    for (int k = 0; k < 6; ++k) out[l + 64 * k] = f2bf(x[k] * sc);
}

// ---------------------------------------------------------------------------
// GEMM body: round-6 proven structure. KCC=64, single-buffered, 2 barriers
// per K-step, 128B-per-row line-aligned global_load_lds, XOR swizzle
// slot' = slot ^ (row&7) (rule #21), bijective XCD remap.
// SUPPORT blocks: pack 2x bf16 per u32 agent-store into Rsup16 + sdone bump
// (opt block consumes). QUERY blocks: plain fp32 stores to Rq.
// Runs on waves 0-3 of a 512-thread block (waves 4-7 exited at kernel top).
// ---------------------------------------------------------------------------
#define MT  128
#define NTP 208
#define KCC 64

__device__ __forceinline__ void gload16(const void* g, void* l) {
    __builtin_amdgcn_global_load_lds(
        (__attribute__((address_space(1))) void*)g,
        (__attribute__((address_space(3))) void*)l, 16, 0, 0);
}

template<int IMG_BASE, int NWG, bool SUPPORT>
__device__ __forceinline__ void gemm_body(
    int gid,
    const unsigned short* __restrict__ Kb,     // [4992][384] bf16, pre /T
    const unsigned short* __restrict__ Qall,   // [100][208][384] bf16
    float* __restrict__ Rq,                    // [75][4900] fp32 (query)
    unsigned short* __restrict__ Rsup16,       // [25][4900] bf16 (support)
    unsigned* counter,
    unsigned short* Asm, unsigned short* Bsm)
{
    int t = threadIdx.x;   // 0..255 here

    // bijective XCD-aware remap (m204)
    constexpr int qq = NWG >> 3;
    constexpr int rr = NWG & 7;
    int xcd = gid & 7;
    int sub = gid >> 3;
    int L = (xcd < rr ? xcd * (qq + 1) : rr * (qq + 1) + (xcd - rr) * qq) + sub;
    int img = IMG_BASE + L / MTILES;
    int m_base = (L % MTILES) * MT;

    const unsigned short* Qimg = Qall + (size_t)img * (QROWS * DIM);

    int wv = t >> 6;        // wave 0..3
    int l  = t & 63;
    int lo = l & 15;        // MFMA frag row/col index
    int hi = l >> 4;        // k-group
    int mh = (wv >> 1) * 64;   // M-half base row
    int nh = wv & 1;           // N-half

    int srow = l >> 3;
    int skp  = (l & 7) ^ srow;      // involution within 8-slot row
    const unsigned short* aSrc = Kb   + (size_t)(m_base + wv * 32 + srow) * DIM + skp * 8;
    const unsigned short* bSrc = Qimg + (size_t)srow * DIM + skp * 8;

    v4f acc[4][7];
    #pragma unroll
    for (int m = 0; m < 4; ++m)
        #pragma unroll
        for (int n = 0; n < 7; ++n)
            acc[m][n] = (v4f){0.f, 0.f, 0.f, 0.f};

    for (int kb = 0; kb < DIM; kb += KCC) {
        #pragma unroll
        for (int j = 0; j < 4; ++j)
            gload16(aSrc + (size_t)j * 8 * DIM + kb,
                    Asm + (wv * 32 + j * 8) * KCC);
        #pragma unroll
        for (int jj = 0; jj < 7; ++jj) {
            int j = wv + jj * 4;
            if (j < 26)
                gload16(bSrc + (size_t)j * 8 * DIM + kb,
                        Bsm + j * 8 * KCC);
        }
        __syncthreads();   // drains vmcnt before LDS reads

        const unsigned short* Ar = Asm + (mh + lo) * KCC;
        const unsigned short* Br = Bsm + (nh * 112 + lo) * KCC;
        #pragma unroll
        for (int kk = 0; kk < 2; ++kk) {
            int koff = ((hi + 4 * kk) ^ (lo & 7)) * 8;   // swizzled k-slot
            v8s a0 = *(const v8s*)(Ar + koff);
            v8s a1 = *(const v8s*)(Ar + 16 * KCC + koff);
            v8s a2 = *(const v8s*)(Ar + 32 * KCC + koff);
            v8s a3 = *(const v8s*)(Ar + 48 * KCC + koff);
            #pragma unroll
            for (int n = 0; n < 7; ++n) {
                if (nh == 0 || n < 6) {   // wave-uniform
                    v8s bb = *(const v8s*)(Br + n * 16 * KCC + koff);
                    acc[0][n] = __builtin_amdgcn_mfma_f32_16x16x32_bf16(a0, bb, acc[0][n], 0, 0, 0);
                    acc[1][n] = __builtin_amdgcn_mfma_f32_16x16x32_bf16(a1, bb, acc[1][n], 0, 0, 0);
                    acc[2][n] = __builtin_amdgcn_mfma_f32_16x16x32_bf16(a2, bb, acc[2][n], 0, 0, 0);
                    acc[3][n] = __builtin_amdgcn_mfma_f32_16x16x32_bf16(a3, bb, acc[3][n], 0, 0, 0);
                }
            }
        }
        __syncthreads();
    }

    // epilogue: exp + per-wave column-half sums. C/D: col=lo, row=hi*4+reg.
    float s[4][4];
    #pragma unroll
    for (int m = 0; m < 4; ++m)
        #pragma unroll
        for (int j = 0; j < 4; ++j) s[m][j] = 0.f;
    #pragma unroll
    for (int n = 0; n < 7; ++n) {
        if (nh == 0 || n < 6) {
            bool ok = ((nh * 7 + n) * 16 + lo) < SEQ;
            #pragma unroll
            for (int m = 0; m < 4; ++m)
                #pragma unroll
                for (int j = 0; j < 4; ++j)
                    s[m][j] += ok ? __expf(acc[m][n][j]) : 0.f;
        }
    }
    #pragma unroll
    for (int mm = 1; mm < 16; mm <<= 1) {
        #pragma unroll
        for (int m = 0; m < 4; ++m)
            #pragma unroll
            for (int j = 0; j < 4; ++j)
                s[m][j] += __shfl_xor(s[m][j], mm);
    }
    float* rp = (float*)Asm;   // reuse A LDS: [2][128] row partials
    if (lo == 0) {
        #pragma unroll
        for (int m = 0; m < 4; ++m)
            #pragma unroll
            for (int j = 0; j < 4; ++j)
                rp[nh * 128 + mh + m * 16 + hi * 4 + j] = s[m][j];
    }
    __syncthreads();
    if (SUPPORT) {
        // pack 2 bf16 per u32 agent-store (write-through for the opt block)
        if (t < 64) {
            int gr0 = m_base + 2 * t;
            if (gr0 < LSUP) {   // gr1 = gr0+1 in same 196-block (gr0 even)
                float o0 = rp[2 * t] + rp[128 + 2 * t];
                float o1 = rp[2 * t + 1] + rp[128 + 2 * t + 1];
                if (gr0 / SEQ == img) { o0 = 0.f; o1 = 0.f; }
                unsigned pk = ((unsigned)f2bf(o1) << 16) | (unsigned)f2bf(o0);
                agent_store_u32((unsigned*)Rsup16 + (((size_t)img * LSUP + gr0) >> 1), pk);
            }
        }
        __syncthreads();   // vmcnt(0): stores acked at coherence point
        if (t == 0)
            __hip_atomic_fetch_add(counter, 1u, __ATOMIC_RELAXED, __HIP_MEMORY_SCOPE_AGENT);
    } else {
        if (t < MT) {
            int gr = m_base + t;
            if (gr < LSUP)
                Rq[(size_t)(img - NSUP) * LSUP + gr] = rp[t] + rp[128 + t];
        }
    }
}

// ---------------------------------------------------------------------------
// Kernel 2: MEGA kernel, 3901 blocks x 512.
// id 0: single-block optimizer (all 8 waves; NO cross-block exchange — the
// whole D chain is LDS-internal; streams bf16 support-R from L2, 490KB/step).
// ids 1..975: support GEMM (waves 0-3; waves 4-7 exit).
// ids 976..3900: query GEMM (waves 0-3).
// __launch_bounds__(512,6): 24 waves/CU -> 3 blocks/CU, VGPR cap 85
// (GEMM path uses 84 — occupancy preserved vs the 256-thread version).
// ---------------------------------------------------------------------------
__global__ __launch_bounds__(512, 6) void mega(
    const unsigned short* __restrict__ Kb,
    const unsigned short* __restrict__ Qall,
    float* __restrict__ Rq,             // [75][4900] fp32
    unsigned short* __restrict__ Rsup16,// [25][4900] bf16
    const int* __restrict__ labels,
    unsigned* __restrict__ sdone,       // support-done counter, pre-zeroed
    float* __restrict__ e_out)          // [4900] final e^{v/T}
{
    __shared__ __align__(16) unsigned short Asm[MT * KCC];    // 16 KiB
    __shared__ __align__(16) unsigned short Bsm[NTP * KCC];   // 26 KiB

    int id = blockIdx.x;
    int t = threadIdx.x;
    if (id != 0) {
        if (t >= 256) return;   // waves 4-7 exit; hw barrier tracks remaining
        if (id >= 1 + NSUPWG)
            gemm_body<NSUP, NQWG, false>(id - 1 - NSUPWG, Kb, Qall, Rq, Rsup16,
                                         sdone, Asm, Bsm);
        else
            gemm_body<0, NSUPWG, true>(id - 1, Kb, Qall, Rq, Rsup16,
                                       sdone, Asm, Bsm);
        return;
    }

    // ---- optimizer block: all 5 classes, 512 threads, 8 waves ----
    float* sh  = (float*)Asm;
    float* red = sh;               // [32][25] = 800
    float* Dsm = sh + 800;         // [125]
    float* cfs = sh + 928;         // [125]
    int*   lsm = (int*)(sh + 1056);// [25]

    int wave = t >> 6, lane = t & 63;
    bool act = t < 490;            // threads cover row-pairs 2t,2t+1 of a class

    if (t < NSUP) lsm[t] = labels[t];
    if (t == 0) {
        unsigned spins = 0;
        while (fresh_u32(sdone) < (unsigned)NSUPWG && ++spins < SPIN_LIMIT)
            __builtin_amdgcn_s_sleep(8);
    }
    __syncthreads();

    float vv[NW][2], ee[NW][2];
    #pragma unroll
    for (int w5 = 0; w5 < NW; ++w5) {
        vv[w5][0] = vv[w5][1] = 0.f;
        ee[w5][0] = ee[w5][1] = 1.f;
    }

    // s=0: D0 push only (e=1). s=1..14: grad+update+push. s=15: final update.
    for (int s = 0; s <= OPT_STEPS; ++s) {
        if (s > 0) {
            if (t < 125) {
                int b = t / 5, ww = t - b * 5;
                float Dsum = 0.f;
                #pragma unroll
                for (int k = 0; k < NW; ++k) Dsum += Dsm[b * 5 + k];
                float Dw = Dsm[t];
                cfs[t] = ((Dw / Dsum) - (ww == lsm[b] ? 1.f : 0.f)) * (INV_T / 25.f) / Dw;
            }
            __syncthreads();
        }
        #pragma unroll
        for (int w5 = 0; w5 < NW; ++w5) {
            const unsigned short* Rb = Rsup16 + (size_t)w5 * BLOCK_W + 2 * t;
            if (s > 0 && act) {
                float g0 = 0.f, g1 = 0.f;
                for (int b = 0; b < NSUP; ++b) {
                    unsigned u = *(const unsigned*)(Rb + (size_t)b * LSUP);
                    float c = cfs[b * 5 + w5];
                    g0 += c * __uint_as_float(u << 16);
                    g1 += c * __uint_as_float(u & 0xffff0000u);
                }
                vv[w5][0] -= LR_F * ee[w5][0] * g0;
                ee[w5][0] = __expf(vv[w5][0] * INV_T);
                vv[w5][1] -= LR_F * ee[w5][1] * g1;
                ee[w5][1] = __expf(vv[w5][1] * INV_T);
            }
            if (s < OPT_STEPS) {
                for (int b = 0; b < NSUP; ++b) {
                    float p = 0.f;
                    if (act) {
                        unsigned u = *(const unsigned*)(Rb + (size_t)b * LSUP);
                        p = ee[w5][0] * __uint_as_float(u << 16)
                          + ee[w5][1] * __uint_as_float(u & 0xffff0000u);
                    }
                    p += __shfl_xor(p, 1); p += __shfl_xor(p, 2);
                    p += __shfl_xor(p, 4); p += __shfl_xor(p, 8);
                    if ((lane & 15) == 0)
                        red[(wave * 4 + (lane >> 4)) * 25 + b] = p;
                }
                __syncthreads();
                if (t < NSUP) {
                    float s2 = 0.f;
                    for (int k = 0; k < 32; ++k) s2 += red[k * 25 + t];
                    Dsm[t * 5 + w5] = s2;
                }
                __syncthreads();
            }
        }
    }

    // export e (plain stores; kernel-end writeback covers final_pred)
    #pragma unroll
    for (int w5 = 0; w5 < NW; ++w5) {
        if (act) {
            e_out[w5 * BLOCK_W + 2 * t]     = ee[w5][0];
            e_out[w5 * BLOCK_W + 2 * t + 1] = ee[w5][1];
        }
    }
}

// ---------------------------------------------------------------------------
// Kernel 3: final prediction. 375 blocks (qb*5+w) x 256.
// ---------------------------------------------------------------------------
__global__ __launch_bounds__(256) void final_pred(const float* __restrict__ Rq,
                                                  const float* __restrict__ e_out,
                                                  float* __restrict__ out) {
    __shared__ float ws[4];
    int blk = blockIdx.x;
    int qb = blk / 5, w = blk % 5;
    const float* R  = Rq + (size_t)qb * LSUP + w * BLOCK_W;
    const float* eb = e_out + w * BLOCK_W;
    int t = threadIdx.x;
    float p = 0.f;
    for (int i = t; i < BLOCK_W; i += 256) p += eb[i] * R[i];
    #pragma unroll
    for (int m = 32; m; m >>= 1) p += __shfl_xor(p, m);
    if ((t & 63) == 0) ws[t >> 6] = p;
    __syncthreads();
    if (t == 0) out[blk] = logf(ws[0] + ws[1] + ws[2] + ws[3]);
}

// ---------------------------------------------------------------------------
extern "C" void kernel_launch(void* const* d_in, const int* in_sizes, int n_in,
                              void* d_out, int out_size, void* d_ws, size_t ws_size,
                              hipStream_t stream) {
    const float* sup_key = (const float*)d_in[0];   // [25,196,384]
    const float* sup_qry = (const float*)d_in[1];   // [25,196,384]
    const float* qry     = (const float*)d_in[2];   // [75,196,384]
    const int*   labels  = (const int*)d_in[3];     // [25]
    float* out = (float*)d_out;                     // [75,5]

    char* ws = (char*)d_ws;
    size_t off = 0;
    auto take = [&](size_t bytes) {
        char* p = ws + off;
        off = (off + bytes + 255) & ~(size_t)255;
        return p;
    };
    unsigned short* Kb     = (unsigned short*)take((size_t)LSUP_PAD * DIM * 2);
    unsigned short* Qall   = (unsigned short*)take((size_t)NIMG * QROWS * DIM * 2);
    float*          Rq     = (float*)take((size_t)NQRY * LSUP * 4);
    unsigned short* Rsup16 = (unsigned short*)take((size_t)NSUP * LSUP * 2);
    float*          eout   = (float*)take((size_t)LSUP * 4);
    int*            fl     = (int*)take(256 * 4);
    unsigned*       sdone  = (unsigned*)fl;

    hipMemsetAsync(fl, 0, 256 * 4, stream);

    norm_all<<<(LSUP_PAD + NIMG * QROWS) / 4, 256, 0, stream>>>(
        sup_key, sup_qry, qry, Kb, Qall);

    mega<<<1 + NSUPWG + NQWG, 512, 0, stream>>>(
        Kb, Qall, Rq, Rsup16, labels, sdone, eout);

    final_pred<<<NQRY * NW, 256, 0, stream>>>(Rq, eout, out);
}

// Round 13
// 1454.497 us; speedup vs baseline: 1.2457x; 1.2457x over previous
//
#include <hip/hip_runtime.h>
#include <hip/hip_bf16.h>

// ---- problem constants ----
#define NW 5
#define KS 5
#define SEQ 196
#define DIM 384
#define NSUP 25        // NW*KS support images
#define NQRY 75        // query images
#define NIMG 100       // NSUP + NQRY
#define LSUP 4900      // NSUP*SEQ support rows
#define LSUP_PAD 4992  // 39*128, zero-padded K rows
#define QROWS 208      // padded qs rows per image (13*16)
#define BLOCK_W 980    // KS*SEQ rows per class block
#define OPT_STEPS 15
#define MTILES 39      // LSUP_PAD / MT
#define NSUPWG (NSUP * MTILES)   // 975 support GEMM blocks
#define NQWG   (NQRY * MTILES)   // 2925 query GEMM blocks
#define SPIN_LIMIT (1u << 22)    // hang-proofing

static constexpr float TEMP_F = 0.0510310363f;
static constexpr float INV_T  = 1.0f / TEMP_F;   // ~19.5959
static constexpr float LR_F   = 0.1f;

typedef short v8s __attribute__((ext_vector_type(8)));   // 8 x bf16 frag (4 VGPRs)
typedef float v4f __attribute__((ext_vector_type(4)));   // 4 x f32 acc

__device__ inline unsigned short f2bf(float x) {
    unsigned int u = __float_as_uint(x);
    u += 0x7fffu + ((u >> 16) & 1u);
    return (unsigned short)(u >> 16);
}
__device__ __forceinline__ float bf_lo(unsigned u) { return __uint_as_float(u << 16); }
__device__ __forceinline__ float bf_hi(unsigned u) { return __uint_as_float(u & 0xffff0000u); }

__device__ __forceinline__ unsigned fresh_u32(unsigned* p) {
    return __hip_atomic_fetch_add(p, 0u, __ATOMIC_RELAXED, __HIP_MEMORY_SCOPE_AGENT);
}
__device__ __forceinline__ void agent_store_u32(unsigned* p, unsigned v) {
    __hip_atomic_store(p, v, __ATOMIC_RELAXED, __HIP_MEMORY_SCOPE_AGENT);
}

// ---------------------------------------------------------------------------
// Kernel 1: fused normalize. Wave-per-row.
// ---------------------------------------------------------------------------
__global__ __launch_bounds__(256) void norm_all(const float* __restrict__ supk,
                                                const float* __restrict__ supq,
                                                const float* __restrict__ qry,
                                                unsigned short* __restrict__ Kb,
                                                unsigned short* __restrict__ Qall) {
    int R = blockIdx.x * 4 + (threadIdx.x >> 6);
    int l = threadIdx.x & 63;
    unsigned short* out;
    const float* in;
    float scale;
    if (R < LSUP_PAD) {
        out = Kb + (size_t)R * DIM;
        if (R >= LSUP) {
            #pragma unroll
            for (int k = 0; k < 6; ++k) out[l + 64 * k] = 0;
            return;
        }
        in = supk + (size_t)R * DIM;
        scale = INV_T;
    } else {
        int i = R - LSUP_PAD;
        int img = i / QROWS;
        int r = i - img * QROWS;
        out = Qall + (size_t)i * DIM;
        if (r >= SEQ) {
            #pragma unroll
            for (int k = 0; k < 6; ++k) out[l + 64 * k] = 0;
            return;
        }
        in = (img < NSUP)
            ? supq + ((size_t)img * SEQ + r) * DIM
            : qry  + ((size_t)(img - NSUP) * SEQ + r) * DIM;
        scale = 1.0f;
    }
    float x[6];
    #pragma unroll
    for (int k = 0; k < 6; ++k) x[k] = in[l + 64 * k];
    float s = 0.f;
    #pragma unroll
    for (int k = 0; k < 6; ++k) s += x[k] * x[k];
    #pragma unroll
    for (int m = 1; m < 64; m <<= 1) s += __shfl_xor(s, m);
    float sc = scale / fmaxf(sqrtf(s), 1e-8f);
    #pragma unroll
    for (int k = 0; k < 6; ++k) out[l + 64 * k] = f2bf(x[k] * sc);
}

// ---------------------------------------------------------------------------
// GEMM body: round-6/11 proven structure. KCC=64, single-buffered, 2 barriers
// per K-step, 128B-per-row line-aligned global_load_lds, XOR swizzle
// slot' = slot ^ (row&7) (rule #21), bijective XCD remap. 256 threads,
// __launch_bounds__(256,3) -> VGPR 84, no spills (round-12 lesson: a 512/6
// bound spilled the accumulators to scratch, 12x regression).
// SUPPORT: pack 2x bf16 per u32 agent-store into Rsup16 + sdone bump.
// QUERY: plain fp32 stores to Rq.
// ---------------------------------------------------------------------------
#define MT  128
#define NTP 208
#define KCC 64

__device__ __forceinline__ void gload16(const void* g, void* l) {
    __builtin_amdgcn_global_load_lds(
        (__attribute__((address_space(1))) void*)g,
        (__attribute__((address_space(3))) void*)l, 16, 0, 0);
}

template<int IMG_BASE, int NWG, bool SUPPORT>
__device__ __forceinline__ void gemm_body(
    int gid,
    const unsigned short* __restrict__ Kb,     // [4992][384] bf16, pre /T
    const unsigned short* __restrict__ Qall,   // [100][208][384] bf16
    float* __restrict__ Rq,                    // [75][4900] fp32 (query)
    unsigned short* __restrict__ Rsup16,       // [25][4900] bf16 (support)
    unsigned* counter,
    unsigned short* Asm, unsigned short* Bsm)
{
    int t = threadIdx.x;

    // bijective XCD-aware remap (m204)
    constexpr int qq = NWG >> 3;
    constexpr int rr = NWG & 7;
    int xcd = gid & 7;
    int sub = gid >> 3;
    int L = (xcd < rr ? xcd * (qq + 1) : rr * (qq + 1) + (xcd - rr) * qq) + sub;
    int img = IMG_BASE + L / MTILES;
    int m_base = (L % MTILES) * MT;

    const unsigned short* Qimg = Qall + (size_t)img * (QROWS * DIM);

    int wv = t >> 6;        // wave 0..3
    int l  = t & 63;
    int lo = l & 15;        // MFMA frag row/col index
    int hi = l >> 4;        // k-group
    int mh = (wv >> 1) * 64;   // M-half base row
    int nh = wv & 1;           // N-half

    int srow = l >> 3;
    int skp  = (l & 7) ^ srow;      // involution within 8-slot row
    const unsigned short* aSrc = Kb   + (size_t)(m_base + wv * 32 + srow) * DIM + skp * 8;
    const unsigned short* bSrc = Qimg + (size_t)srow * DIM + skp * 8;

    v4f acc[4][7];
    #pragma unroll
    for (int m = 0; m < 4; ++m)
        #pragma unroll
        for (int n = 0; n < 7; ++n)
            acc[m][n] = (v4f){0.f, 0.f, 0.f, 0.f};

    for (int kb = 0; kb < DIM; kb += KCC) {
        #pragma unroll
        for (int j = 0; j < 4; ++j)
            gload16(aSrc + (size_t)j * 8 * DIM + kb,
                    Asm + (wv * 32 + j * 8) * KCC);
        #pragma unroll
        for (int jj = 0; jj < 7; ++jj) {
            int j = wv + jj * 4;
            if (j < 26)
                gload16(bSrc + (size_t)j * 8 * DIM + kb,
                        Bsm + j * 8 * KCC);
        }
        __syncthreads();   // drains vmcnt before LDS reads

        const unsigned short* Ar = Asm + (mh + lo) * KCC;
        const unsigned short* Br = Bsm + (nh * 112 + lo) * KCC;
        #pragma unroll
        for (int kk = 0; kk < 2; ++kk) {
            int koff = ((hi + 4 * kk) ^ (lo & 7)) * 8;   // swizzled k-slot
            v8s a0 = *(const v8s*)(Ar + koff);
            v8s a1 = *(const v8s*)(Ar + 16 * KCC + koff);
            v8s a2 = *(const v8s*)(Ar + 32 * KCC + koff);
            v8s a3 = *(const v8s*)(Ar + 48 * KCC + koff);
            #pragma unroll
            for (int n = 0; n < 7; ++n) {
                if (nh == 0 || n < 6) {   // wave-uniform
                    v8s bb = *(const v8s*)(Br + n * 16 * KCC + koff);
                    acc[0][n] = __builtin_amdgcn_mfma_f32_16x16x32_bf16(a0, bb, acc[0][n], 0, 0, 0);
                    acc[1][n] = __builtin_amdgcn_mfma_f32_16x16x32_bf16(a1, bb, acc[1][n], 0, 0, 0);
                    acc[2][n] = __builtin_amdgcn_mfma_f32_16x16x32_bf16(a2, bb, acc[2][n], 0, 0, 0);
                    acc[3][n] = __builtin_amdgcn_mfma_f32_16x16x32_bf16(a3, bb, acc[3][n], 0, 0, 0);
                }
            }
        }
        __syncthreads();
    }

    // epilogue: exp + per-wave column-half sums. C/D: col=lo, row=hi*4+reg.
    float s[4][4];
    #pragma unroll
    for (int m = 0; m < 4; ++m)
        #pragma unroll
        for (int j = 0; j < 4; ++j) s[m][j] = 0.f;
    #pragma unroll
    for (int n = 0; n < 7; ++n) {
        if (nh == 0 || n < 6) {
            bool ok = ((nh * 7 + n) * 16 + lo) < SEQ;
            #pragma unroll
            for (int m = 0; m < 4; ++m)
                #pragma unroll
                for (int j = 0; j < 4; ++j)
                    s[m][j] += ok ? __expf(acc[m][n][j]) : 0.f;
        }
    }
    #pragma unroll
    for (int mm = 1; mm < 16; mm <<= 1) {
        #pragma unroll
        for (int m = 0; m < 4; ++m)
            #pragma unroll
            for (int j = 0; j < 4; ++j)
                s[m][j] += __shfl_xor(s[m][j], mm);
    }
    float* rp = (float*)Asm;   // reuse A LDS: [2][128] row partials
    if (lo == 0) {
        #pragma unroll
        for (int m = 0; m < 4; ++m)
            #pragma unroll
            for (int j = 0; j < 4; ++j)
                rp[nh * 128 + mh + m * 16 + hi * 4 + j] = s[m][j];
    }
    __syncthreads();
    if (SUPPORT) {
        // pack 2 bf16 per u32 agent-store; pairs (even,odd) never straddle
        // a 196-row image block (block starts are even).
        if (t < 64) {
            int gr0 = m_base + 2 * t;
            if (gr0 < LSUP) {
                float o0 = rp[2 * t] + rp[128 + 2 * t];
                float o1 = rp[2 * t + 1] + rp[128 + 2 * t + 1];
                if (gr0 / SEQ == img) { o0 = 0.f; o1 = 0.f; }
                unsigned pk = ((unsigned)f2bf(o1) << 16) | (unsigned)f2bf(o0);
                agent_store_u32((unsigned*)Rsup16 + (((size_t)img * LSUP + gr0) >> 1), pk);
            }
        }
        __syncthreads();   // vmcnt(0): stores acked at coherence point
        if (t == 0)
            __hip_atomic_fetch_add(counter, 1u, __ATOMIC_RELAXED, __HIP_MEMORY_SCOPE_AGENT);
    } else {
        if (t < MT) {
            int gr = m_base + t;
            if (gr < LSUP)
                Rq[(size_t)(img - NSUP) * LSUP + gr] = rp[t] + rp[128 + t];
        }
    }
}

// ---------------------------------------------------------------------------
// Kernel 2: MEGA kernel, 3901 blocks x 256.
// id 0: SINGLE-block optimizer — all 5 classes, D chain entirely LDS-internal
// (zero cross-block exchanges; only sync = one-time sdone wait). Streams the
// bf16-packed support R (245 KB, L2-resident) twice per step.
// ids 1..975: support GEMM. ids 976..3900: query GEMM.
// ---------------------------------------------------------------------------
__global__ __launch_bounds__(256, 3) void mega(
    const unsigned short* __restrict__ Kb,
    const unsigned short* __restrict__ Qall,
    float* __restrict__ Rq,             // [75][4900] fp32
    unsigned short* __restrict__ Rsup16,// [25][4900] bf16
    const int* __restrict__ labels,
    unsigned* __restrict__ sdone,       // support-done counter, pre-zeroed
    float* __restrict__ e_out)          // [4900] final e^{v/T}
{
    __shared__ __align__(16) unsigned short Asm[MT * KCC];    // 16 KiB
    __shared__ __align__(16) unsigned short Bsm[NTP * KCC];   // 26 KiB

    int id = blockIdx.x;
    int t = threadIdx.x;
    if (id != 0) {
        if (id >= 1 + NSUPWG)
            gemm_body<NSUP, NQWG, false>(id - 1 - NSUPWG, Kb, Qall, Rq, Rsup16,
                                         sdone, Asm, Bsm);
        else
            gemm_body<0, NSUPWG, true>(id - 1, Kb, Qall, Rq, Rsup16,
                                       sdone, Asm, Bsm);
        return;
    }

    // ---- single-block optimizer ----
    float* sh  = (float*)Asm;
    float* red = sh;               // [4][25]
    float* Dsm = sh + 100;         // [125]  D[b*5+w]
    float* cfs = sh + 228;         // [125]  coeff[b*5+w]
    int*   lsm = (int*)(sh + 356); // [25]

    int wave = t >> 6, lane = t & 63;
    bool act1 = t < (490 - 256);   // pair i1 = t+256 valid (i1 < 490)

    if (t < NSUP) lsm[t] = labels[t];
    if (t == 0) {
        unsigned spins = 0;
        while (fresh_u32(sdone) < (unsigned)NSUPWG && ++spins < SPIN_LIMIT)
            __builtin_amdgcn_s_sleep(8);
    }
    __syncthreads();

    // u32 view: R32[b*2450 + w*490 + i] packs rows (2i, 2i+1) of class w.
    const unsigned* R32 = (const unsigned*)Rsup16;

    // per-thread state: pairs i0=t, i1=t+256; 4 rows/class.
    float vv[NW][4], ee[NW][4];
    #pragma unroll
    for (int w5 = 0; w5 < NW; ++w5)
        #pragma unroll
        for (int k = 0; k < 4; ++k) { vv[w5][k] = 0.f; ee[w5][k] = 1.f; }

    // s=0: D0 push only (e=1). s=1..14: grad+update+push. s=15: final update.
    for (int s = 0; s <= OPT_STEPS; ++s) {
        if (s > 0) {
            if (t < 125) {
                int b = t / 5, ww = t - b * 5;
                float Dsum = 0.f;
                #pragma unroll
                for (int k = 0; k < NW; ++k) Dsum += Dsm[b * 5 + k];
                float Dw = Dsm[t];
                cfs[t] = ((Dw / Dsum) - (ww == lsm[b] ? 1.f : 0.f)) * (INV_T / 25.f) / Dw;
            }
            __syncthreads();
        }
        #pragma unroll
        for (int w5 = 0; w5 < NW; ++w5) {
            const unsigned* Rw = R32 + w5 * 490;
            if (s > 0) {
                float g0 = 0.f, g1 = 0.f, g2 = 0.f, g3 = 0.f;
                for (int b = 0; b < NSUP; ++b) {
                    unsigned u0 = Rw[b * 2450 + t];
                    unsigned u1 = act1 ? Rw[b * 2450 + t + 256] : 0u;
                    float c = cfs[b * 5 + w5];
                    g0 += c * bf_lo(u0); g1 += c * bf_hi(u0);
                    g2 += c * bf_lo(u1); g3 += c * bf_hi(u1);
                }
                vv[w5][0] -= LR_F * ee[w5][0] * g0; ee[w5][0] = __expf(vv[w5][0] * INV_T);
                vv[w5][1] -= LR_F * ee[w5][1] * g1; ee[w5][1] = __expf(vv[w5][1] * INV_T);
                vv[w5][2] -= LR_F * ee[w5][2] * g2; ee[w5][2] = __expf(vv[w5][2] * INV_T);
                vv[w5][3] -= LR_F * ee[w5][3] * g3; ee[w5][3] = __expf(vv[w5][3] * INV_T);
            }
            if (s < OPT_STEPS) {
                for (int b = 0; b < NSUP; ++b) {
                    unsigned u0 = Rw[b * 2450 + t];
                    unsigned u1 = act1 ? Rw[b * 2450 + t + 256] : 0u;
                    float p = ee[w5][0] * bf_lo(u0) + ee[w5][1] * bf_hi(u0)
                            + ee[w5][2] * bf_lo(u1) + ee[w5][3] * bf_hi(u1);
                    #pragma unroll
                    for (int m = 1; m < 64; m <<= 1) p += __shfl_xor(p, m);
                    if (lane == 0) red[wave * 25 + b] = p;
                }
                __syncthreads();
                if (t < NSUP)
                    Dsm[t * 5 + w5] = red[t] + red[25 + t] + red[50 + t] + red[75 + t];
                __syncthreads();
            }
        }
    }

    // export e (plain stores; kernel-end writeback covers final_pred)
    #pragma unroll
    for (int w5 = 0; w5 < NW; ++w5) {
        e_out[w5 * BLOCK_W + 2 * t]     = ee[w5][0];
        e_out[w5 * BLOCK_W + 2 * t + 1] = ee[w5][1];
        if (act1) {
            e_out[w5 * BLOCK_W + 2 * (t + 256)]     = ee[w5][2];
            e_out[w5 * BLOCK_W + 2 * (t + 256) + 1] = ee[w5][3];
        }
    }
}

// ---------------------------------------------------------------------------
// Kernel 3: final prediction. 375 blocks (qb*5+w) x 256.
// ---------------------------------------------------------------------------
__global__ __launch_bounds__(256) void final_pred(const float* __restrict__ Rq,
                                                  const float* __restrict__ e_out,
                                                  float* __restrict__ out) {
    __shared__ float ws[4];
    int blk = blockIdx.x;
    int qb = blk / 5, w = blk % 5;
    const float* R  = Rq + (size_t)qb * LSUP + w * BLOCK_W;
    const float* eb = e_out + w * BLOCK_W;
    int t = threadIdx.x;
    float p = 0.f;
    for (int i = t; i < BLOCK_W; i += 256) p += eb[i] * R[i];
    #pragma unroll
    for (int m = 32; m; m >>= 1) p += __shfl_xor(p, m);
    if ((t & 63) == 0) ws[t >> 6] = p;
    __syncthreads();
    if (t == 0) out[blk] = logf(ws[0] + ws[1] + ws[2] + ws[3]);
}

// ---------------------------------------------------------------------------
extern "C" void kernel_launch(void* const* d_in, const int* in_sizes, int n_in,
                              void* d_out, int out_size, void* d_ws, size_t ws_size,
                              hipStream_t stream) {
    const float* sup_key = (const float*)d_in[0];   // [25,196,384]
    const float* sup_qry = (const float*)d_in[1];   // [25,196,384]
    const float* qry     = (const float*)d_in[2];   // [75,196,384]
    const int*   labels  = (const int*)d_in[3];     // [25]
    float* out = (float*)d_out;                     // [75,5]

    char* ws = (char*)d_ws;
    size_t off = 0;
    auto take = [&](size_t bytes) {
        char* p = ws + off;
        off = (off + bytes + 255) & ~(size_t)255;
        return p;
    };
    unsigned short* Kb     = (unsigned short*)take((size_t)LSUP_PAD * DIM * 2);
    unsigned short* Qall   = (unsigned short*)take((size_t)NIMG * QROWS * DIM * 2);
    float*          Rq     = (float*)take((size_t)NQRY * LSUP * 4);
    unsigned short* Rsup16 = (unsigned short*)take((size_t)NSUP * LSUP * 2);
    float*          eout   = (float*)take((size_t)LSUP * 4);
    int*            fl     = (int*)take(256 * 4);
    unsigned*       sdone  = (unsigned*)fl;

    hipMemsetAsync(fl, 0, 256 * 4, stream);

    norm_all<<<(LSUP_PAD + NIMG * QROWS) / 4, 256, 0, stream>>>(
        sup_key, sup_qry, qry, Kb, Qall);

    mega<<<1 + NSUPWG + NQWG, 256, 0, stream>>>(
        Kb, Qall, Rq, Rsup16, labels, sdone, eout);

    final_pred<<<NQRY * NW, 256, 0, stream>>>(Rq, eout, out);
}

// Round 14
// 225.527 us; speedup vs baseline: 8.0339x; 6.4493x over previous
//
#include <hip/hip_runtime.h>
#include <hip/hip_bf16.h>

// ---- problem constants ----
#define NW 5
#define KS 5
#define SEQ 196
#define DIM 384
#define NSUP 25        // NW*KS support images
#define NQRY 75        // query images
#define NIMG 100       // NSUP + NQRY
#define LSUP 4900      // NSUP*SEQ support rows
#define LSUP_PAD 4992  // 39*128, zero-padded K rows
#define QROWS 208      // padded qs rows per image (13*16)
#define BLOCK_W 980    // KS*SEQ rows per class block
#define OPT_STEPS 15
#define MTILES 39      // LSUP_PAD / MT
#define NSUPWG (NSUP * MTILES)   // 975 support GEMM blocks
#define NQWG   (NQRY * MTILES)   // 2925 query GEMM blocks
#define NORMWG ((LSUP_PAD + NIMG * QROWS) / 4)   // 6448 norm blocks
#define SPIN_LIMIT (1u << 22)    // hang-proofing

static constexpr float TEMP_F = 0.0510310363f;
static constexpr float INV_T  = 1.0f / TEMP_F;   // ~19.5959
static constexpr float LR_F   = 0.1f;

typedef short v8s __attribute__((ext_vector_type(8)));   // 8 x bf16 frag (4 VGPRs)
typedef float v4f __attribute__((ext_vector_type(4)));   // 4 x f32 acc

__device__ inline unsigned short f2bf(float x) {
    unsigned int u = __float_as_uint(x);
    u += 0x7fffu + ((u >> 16) & 1u);
    return (unsigned short)(u >> 16);
}

// agent-scope ops execute at the fabric coherence point (cross-XCD correct).
// RMW reads (fetch_add 0) are guaranteed-fresh there.
__device__ __forceinline__ float fresh_f32(float* p) {
    return __hip_atomic_fetch_add(p, 0.0f, __ATOMIC_RELAXED, __HIP_MEMORY_SCOPE_AGENT);
}
__device__ __forceinline__ int fresh_i32(int* p) {
    return __hip_atomic_fetch_add(p, 0, __ATOMIC_RELAXED, __HIP_MEMORY_SCOPE_AGENT);
}
__device__ __forceinline__ unsigned fresh_u32(unsigned* p) {
    return __hip_atomic_fetch_add(p, 0u, __ATOMIC_RELAXED, __HIP_MEMORY_SCOPE_AGENT);
}
__device__ __forceinline__ void agent_store_f32(float* p, float v) {
    __hip_atomic_store(p, v, __ATOMIC_RELAXED, __HIP_MEMORY_SCOPE_AGENT);
}
__device__ __forceinline__ void agent_store_i32(int* p, int v) {
    __hip_atomic_store(p, v, __ATOMIC_RELAXED, __HIP_MEMORY_SCOPE_AGENT);
}

// ---------------------------------------------------------------------------
// Kernel 1: fused normalize. Wave-per-row. Block NORMWG zeroes Dbuf/flags
// (replaces two hipMemsetAsync dispatches).
// ---------------------------------------------------------------------------
__global__ __launch_bounds__(256) void norm_all(const float* __restrict__ supk,
                                                const float* __restrict__ supq,
                                                const float* __restrict__ qry,
                                                unsigned short* __restrict__ Kb,
                                                unsigned short* __restrict__ Qall,
                                                float* __restrict__ zbuf) {
    if (blockIdx.x == NORMWG) {
        for (int i = threadIdx.x; i < (OPT_STEPS + 1) * 125 + 64; i += 256)
            zbuf[i] = 0.f;
        return;
    }
    int R = blockIdx.x * 4 + (threadIdx.x >> 6);
    int l = threadIdx.x & 63;
    unsigned short* out;
    const float* in;
    float scale;
    if (R < LSUP_PAD) {
        out = Kb + (size_t)R * DIM;
        if (R >= LSUP) {
            #pragma unroll
            for (int k = 0; k < 6; ++k) out[l + 64 * k] = 0;
            return;
        }
        in = supk + (size_t)R * DIM;
        scale = INV_T;
    } else {
        int i = R - LSUP_PAD;
        int img = i / QROWS;
        int r = i - img * QROWS;
        out = Qall + (size_t)i * DIM;
        if (r >= SEQ) {
            #pragma unroll
            for (int k = 0; k < 6; ++k) out[l + 64 * k] = 0;
            return;
        }
        in = (img < NSUP)
            ? supq + ((size_t)img * SEQ + r) * DIM
            : qry  + ((size_t)(img - NSUP) * SEQ + r) * DIM;
        scale = 1.0f;
    }
    float x[6];
    #pragma unroll
    for (int k = 0; k < 6; ++k) x[k] = in[l + 64 * k];
    float s = 0.f;
    #pragma unroll
    for (int k = 0; k < 6; ++k) s += x[k] * x[k];
    #pragma unroll
    for (int m = 1; m < 64; m <<= 1) s += __shfl_xor(s, m);
    float sc = scale / fmaxf(sqrtf(s), 1e-8f);
    #pragma unroll
    for (int k = 0; k < 6; ++k) out[l + 64 * k] = f2bf(x[k] * sc);
}

// ---------------------------------------------------------------------------
// GEMM body: round-6 proven structure (mega=145us). KCC=64, single-buffered,
// 2 barriers per K-step, 128B-per-row line-aligned global_load_lds, XOR
// swizzle slot' = slot ^ (row&7) (rule #21), bijective XCD remap.
// SUPPORT blocks additionally: (a) write R via agent-scope (sc1) stores so
// co-resident opt blocks can read; (b) LDS-reduce their rows' exp-sums per
// class segment and atomicAdd into D0 = Dbuf[0] (so opt blocks skip the
// whole step-0 exchange — D0 readiness coincides with sdone); (c) bump sdone.
// QUERY blocks: plain fp32 stores (round-9 lesson: sc1 for 2925 blocks ~2x).
// ---------------------------------------------------------------------------
#define MT  128
#define NTP 208
#define KCC 64

__device__ __forceinline__ void gload16(const void* g, void* l) {
    __builtin_amdgcn_global_load_lds(
        (__attribute__((address_space(1))) void*)g,
        (__attribute__((address_space(3))) void*)l, 16, 0, 0);
}

template<int IMG_BASE, int NWG, bool SUPPORT>
__device__ __forceinline__ void gemm_body(
    int gid,
    const unsigned short* __restrict__ Kb,     // [4992][384] bf16, pre /T
    const unsigned short* __restrict__ Qall,   // [100][208][384] bf16
    float* __restrict__ Rall,
    float* __restrict__ D0,                    // Dbuf step-0 block [25*5]
    unsigned* counter,
    unsigned short* Asm, unsigned short* Bsm)
{
    int t = threadIdx.x;

    // bijective XCD-aware remap (m204)
    constexpr int qq = NWG >> 3;
    constexpr int rr = NWG & 7;
    int xcd = gid & 7;
    int sub = gid >> 3;
    int L = (xcd < rr ? xcd * (qq + 1) : rr * (qq + 1) + (xcd - rr) * qq) + sub;
    int img = IMG_BASE + L / MTILES;
    int m_base = (L % MTILES) * MT;

    const unsigned short* Qimg = Qall + (size_t)img * (QROWS * DIM);

    int wv = t >> 6;        // wave 0..3
    int l  = t & 63;
    int lo = l & 15;        // MFMA frag row/col index
    int hi = l >> 4;        // k-group
    int mh = (wv >> 1) * 64;   // M-half base row
    int nh = wv & 1;           // N-half

    int srow = l >> 3;
    int skp  = (l & 7) ^ srow;      // involution within 8-slot row
    const unsigned short* aSrc = Kb   + (size_t)(m_base + wv * 32 + srow) * DIM + skp * 8;
    const unsigned short* bSrc = Qimg + (size_t)srow * DIM + skp * 8;

    v4f acc[4][7];
    #pragma unroll
    for (int m = 0; m < 4; ++m)
        #pragma unroll
        for (int n = 0; n < 7; ++n)
            acc[m][n] = (v4f){0.f, 0.f, 0.f, 0.f};

    for (int kb = 0; kb < DIM; kb += KCC) {
        #pragma unroll
        for (int j = 0; j < 4; ++j)
            gload16(aSrc + (size_t)j * 8 * DIM + kb,
                    Asm + (wv * 32 + j * 8) * KCC);
        #pragma unroll
        for (int jj = 0; jj < 7; ++jj) {
            int j = wv + jj * 4;
            if (j < 26)
                gload16(bSrc + (size_t)j * 8 * DIM + kb,
                        Bsm + j * 8 * KCC);
        }
        __syncthreads();   // drains vmcnt before LDS reads

        const unsigned short* Ar = Asm + (mh + lo) * KCC;
        const unsigned short* Br = Bsm + (nh * 112 + lo) * KCC;
        #pragma unroll
        for (int kk = 0; kk < 2; ++kk) {
            int koff = ((hi + 4 * kk) ^ (lo & 7)) * 8;   // swizzled k-slot
            v8s a0 = *(const v8s*)(Ar + koff);
            v8s a1 = *(const v8s*)(Ar + 16 * KCC + koff);
            v8s a2 = *(const v8s*)(Ar + 32 * KCC + koff);
            v8s a3 = *(const v8s*)(Ar + 48 * KCC + koff);
            #pragma unroll
            for (int n = 0; n < 7; ++n) {
                if (nh == 0 || n < 6) {   // wave-uniform
                    v8s bb = *(const v8s*)(Br + n * 16 * KCC + koff);
                    acc[0][n] = __builtin_amdgcn_mfma_f32_16x16x32_bf16(a0, bb, acc[0][n], 0, 0, 0);
                    acc[1][n] = __builtin_amdgcn_mfma_f32_16x16x32_bf16(a1, bb, acc[1][n], 0, 0, 0);
                    acc[2][n] = __builtin_amdgcn_mfma_f32_16x16x32_bf16(a2, bb, acc[2][n], 0, 0, 0);
                    acc[3][n] = __builtin_amdgcn_mfma_f32_16x16x32_bf16(a3, bb, acc[3][n], 0, 0, 0);
                }
            }
        }
        __syncthreads();
    }

    // epilogue: exp + per-wave column-half sums. C/D: col=lo, row=hi*4+reg.
    float s[4][4];
    #pragma unroll
    for (int m = 0; m < 4; ++m)
        #pragma unroll
        for (int j = 0; j < 4; ++j) s[m][j] = 0.f;
    #pragma unroll
    for (int n = 0; n < 7; ++n) {
        if (nh == 0 || n < 6) {
            bool ok = ((nh * 7 + n) * 16 + lo) < SEQ;
            #pragma unroll
            for (int m = 0; m < 4; ++m)
                #pragma unroll
                for (int j = 0; j < 4; ++j)
                    s[m][j] += ok ? __expf(acc[m][n][j]) : 0.f;
        }
    }
    #pragma unroll
    for (int mm = 1; mm < 16; mm <<= 1) {
        #pragma unroll
        for (int m = 0; m < 4; ++m)
            #pragma unroll
            for (int j = 0; j < 4; ++j)
                s[m][j] += __shfl_xor(s[m][j], mm);
    }
    float* rp = (float*)Asm;   // reuse A LDS: [2][128] row partials
    if (lo == 0) {
        #pragma unroll
        for (int m = 0; m < 4; ++m)
            #pragma unroll
            for (int j = 0; j < 4; ++j)
                rp[nh * 128 + mh + m * 16 + hi * 4 + j] = s[m][j];
    }
    if (SUPPORT && t == 0) { rp[256] = 0.f; rp[257] = 0.f; }  // D0 partials
    __syncthreads();
    int w0 = m_base / BLOCK_W;
    if (t < MT) {
        int gr = m_base + t;
        if (gr < LSUP) {
            float o = rp[t] + rp[128 + t];
            if (img < NSUP && (gr / SEQ) == img) o = 0.f;
            if (SUPPORT) {   // write-through so co-resident opt blocks see it
                agent_store_f32(&Rall[(size_t)img * LSUP + gr], o);
                atomicAdd(&rp[256 + (gr / BLOCK_W - w0)], o);  // LDS atomic
            } else {
                Rall[(size_t)img * LSUP + gr] = o;
            }
        }
    }
    if (SUPPORT) {
        __syncthreads();   // LDS D0 partials complete
        if (t < 2) {
            int w = w0 + t;
            if (w < NW && w * BLOCK_W < m_base + MT)   // class intersects tile
                atomicAdd(&D0[img * 5 + w], rp[256 + t]);  // device-scope
        }
        __syncthreads();   // vmcnt(0): sc1 stores + atomics acked
        if (t == 0)
            __hip_atomic_fetch_add(counter, 1u, __ATOMIC_RELAXED, __HIP_MEMORY_SCOPE_AGENT);
    }
}

// ---------------------------------------------------------------------------
// Kernel 2: MEGA kernel, 3905 blocks x 256 (round-6 structure, best measured).
// ids 0..4: optimizer (class w = id). ids 5..979: support GEMM.
// ids 980..3904: query GEMM.
// Exchange: interleaved Dbuf[step*125 + b*5 + w] agent stores + one flag per
// producer; consumers one-shot agent-RMW read all 125. D0 comes from the
// support blocks' atomics (readiness == sdone), so the opt skips pushD(0)
// and the step-0 poll entirely (one fewer fabric round-trip on the chain).
// flags[w] = k  <=>  D(k) published (k = 1..14). All spins bounded.
// ---------------------------------------------------------------------------
__global__ __launch_bounds__(256, 3) void mega(
    const unsigned short* __restrict__ Kb,
    const unsigned short* __restrict__ Qall,
    float* __restrict__ Rall,
    const int* __restrict__ labels,
    float* __restrict__ Dbufs,      // [16][125], pre-zeroed (norm_all)
    int* __restrict__ flags,        // [8], pre-zeroed
    unsigned* __restrict__ sdone,   // support-done counter, pre-zeroed
    float* __restrict__ e_out)      // [4900] final e^{v/T}
{
    __shared__ __align__(16) unsigned short Asm[MT * KCC];    // 16 KiB
    __shared__ __align__(16) unsigned short Bsm[NTP * KCC];   // 26 KiB

    int id = blockIdx.x;
    if (id >= NW + NSUPWG) {
        gemm_body<NSUP, NQWG, false>(id - (NW + NSUPWG), Kb, Qall, Rall,
                                     Dbufs, sdone, Asm, Bsm);
        return;
    }
    if (id >= NW) {
        gemm_body<0, NSUPWG, true>(id - NW, Kb, Qall, Rall,
                                   Dbufs, sdone, Asm, Bsm);
        return;
    }

    // ---- optimizer block for class w ----
    float* sh  = (float*)Asm;
    float* red = sh;              // [4][25]
    float* cfs = sh + 100;        // [25]
    float* Dsm = sh + 128;        // [125]
    int*   lsm = (int*)(sh + 256);// [25]

    int w = id;
    int t = threadIdx.x;
    int wave = t >> 6, lane = t & 63;

    // wait for all 975 support blocks (R and D0 both ready at this point)
    if (t == 0) {
        unsigned spins = 0;
        while (fresh_u32(sdone) < (unsigned)NSUPWG && ++spins < SPIN_LIMIT)
            __builtin_amdgcn_s_sleep(8);
    }
    __syncthreads();

    // rows r = t + 256k, k<4 (k=3 valid only for t<212); inactive rows -> 0.
    float Rv[4][NSUP];
    #pragma unroll
    for (int b = 0; b < NSUP; ++b) {
        const float* Rb = Rall + (size_t)b * LSUP + w * BLOCK_W;
        Rv[0][b] = Rb[t];
        Rv[1][b] = Rb[t + 256];
        Rv[2][b] = Rb[t + 512];
        Rv[3][b] = (t < BLOCK_W - 768) ? Rb[t + 768] : 0.f;
    }
    if (t < NSUP) lsm[t] = labels[t];

    float e0 = 1.f, e1 = 1.f, e2 = 1.f, e3 = 1.f;
    float v0 = 0.f, v1 = 0.f, v2 = 0.f, v3 = 0.f;

    auto pushD = [&](int step) {
        float part[NSUP];
        #pragma unroll
        for (int b = 0; b < NSUP; ++b)
            part[b] = e0 * Rv[0][b] + e1 * Rv[1][b] + e2 * Rv[2][b] + e3 * Rv[3][b];
        #pragma unroll
        for (int b = 0; b < NSUP; ++b) {
            #pragma unroll
            for (int m = 32; m; m >>= 1) part[b] += __shfl_xor(part[b], m);
        }
        if (lane == 0) {
            #pragma unroll
            for (int b = 0; b < NSUP; ++b) red[wave * NSUP + b] = part[b];
        }
        __syncthreads();
        if (t < NSUP) {
            float s = red[t] + red[NSUP + t] + red[2 * NSUP + t] + red[3 * NSUP + t];
            agent_store_f32(&Dbufs[step * 125 + t * 5 + w], s);
        }
        __syncthreads();   // vmcnt(0) drain: payload acked at coherence point
        if (t == 0)
            agent_store_i32(&flags[w], step);
    };

    for (int s = 0; s < OPT_STEPS; ++s) {
        // wait for step-s D. s=0: ready via sdone (support atomics) — no poll.
        if (s > 0 && wave == 0) {
            unsigned spins = 0;
            for (;;) {
                int f = (lane < NW) ? fresh_i32(&flags[lane]) : 0x7fffffff;
                if (__all(f >= s)) break;
                if (++spins >= SPIN_LIMIT) break;
                __builtin_amdgcn_s_sleep(1);
            }
        }
        __syncthreads();
        if (t < 125)
            Dsm[t] = fresh_f32(&Dbufs[s * 125 + t]);
        __syncthreads();
        if (t < NSUP) {
            float Dsum = 0.f, Dw = 1.f;
            #pragma unroll
            for (int ww = 0; ww < NW; ++ww) {
                float d = Dsm[t * 5 + ww];
                Dsum += d;
                if (ww == w) Dw = d;
            }
            cfs[t] = ((Dw / Dsum) - (w == lsm[t] ? 1.f : 0.f)) * (INV_T / 25.f) / Dw;
        }
        __syncthreads();
        float g0 = 0.f, g1 = 0.f, g2 = 0.f, g3 = 0.f;
        #pragma unroll
        for (int b = 0; b < NSUP; ++b) {
            float c = cfs[b];
            g0 += c * Rv[0][b];
            g1 += c * Rv[1][b];
            g2 += c * Rv[2][b];
            g3 += c * Rv[3][b];
        }
        v0 -= LR_F * e0 * g0; e0 = __expf(v0 * INV_T);
        v1 -= LR_F * e1 * g1; e1 = __expf(v1 * INV_T);
        v2 -= LR_F * e2 * g2; e2 = __expf(v2 * INV_T);
        v3 -= LR_F * e3 * g3; e3 = __expf(v3 * INV_T);
        __syncthreads();      // red/Dsm/cfs reuse protection
        if (s + 1 < OPT_STEPS) pushD(s + 1);
    }

    // export e (plain stores; kernel-end writeback covers final_pred)
    float* eo = e_out + w * BLOCK_W;
    eo[t]       = e0;
    eo[t + 256] = e1;
    eo[t + 512] = e2;
    if (t < BLOCK_W - 768) eo[t + 768] = e3;
}

// ---------------------------------------------------------------------------
// Kernel 3: final prediction. 375 blocks (qb*5+w) x 256.
// ---------------------------------------------------------------------------
__global__ __launch_bounds__(256) void final_pred(const float* __restrict__ Rall,
                                                  const float* __restrict__ e_out,
                                                  float* __restrict__ out) {
    __shared__ float ws[4];
    int blk = blockIdx.x;
    int qb = blk / 5, w = blk % 5;
    const float* R  = Rall + (size_t)(NSUP + qb) * LSUP + w * BLOCK_W;
    const float* eb = e_out + w * BLOCK_W;
    int t = threadIdx.x;
    float p = 0.f;
    for (int i = t; i < BLOCK_W; i += 256) p += eb[i] * R[i];
    #pragma unroll
    for (int m = 32; m; m >>= 1) p += __shfl_xor(p, m);
    if ((t & 63) == 0) ws[t >> 6] = p;
    __syncthreads();
    if (t == 0) out[blk] = logf(ws[0] + ws[1] + ws[2] + ws[3]);
}

// ---------------------------------------------------------------------------
extern "C" void kernel_launch(void* const* d_in, const int* in_sizes, int n_in,
                              void* d_out, int out_size, void* d_ws, size_t ws_size,
                              hipStream_t stream) {
    const float* sup_key = (const float*)d_in[0];   // [25,196,384]
    const float* sup_qry = (const float*)d_in[1];   // [25,196,384]
    const float* qry     = (const float*)d_in[2];   // [75,196,384]
    const int*   labels  = (const int*)d_in[3];     // [25]
    float* out = (float*)d_out;                     // [75,5]

    char* ws = (char*)d_ws;
    size_t off = 0;
    auto take = [&](size_t bytes) {
        char* p = ws + off;
        off = (off + bytes + 255) & ~(size_t)255;
        return p;
    };
    unsigned short* Kb   = (unsigned short*)take((size_t)LSUP_PAD * DIM * 2);
    unsigned short* Qall = (unsigned short*)take((size_t)NIMG * QROWS * DIM * 2);
    float*          Rall = (float*)take((size_t)NIMG * LSUP * 4);
    float*          Dbuf = (float*)take(((size_t)(OPT_STEPS + 1) * 125 + 64) * 4);
    float*          eout = (float*)take((size_t)LSUP * 4);
    int*            flags = (int*)(Dbuf + (OPT_STEPS + 1) * 125);
    unsigned*       sdone = (unsigned*)(flags + 16);

    norm_all<<<NORMWG + 1, 256, 0, stream>>>(
        sup_key, sup_qry, qry, Kb, Qall, Dbuf);

    mega<<<NW + NSUPWG + NQWG, 256, 0, stream>>>(
        Kb, Qall, Rall, labels, Dbuf, flags, sdone, eout);

    final_pred<<<NQRY * NW, 256, 0, stream>>>(Rall, eout, out);
}

// Round 15
// 217.973 us; speedup vs baseline: 8.3123x; 1.0347x over previous
//
#include <hip/hip_runtime.h>
#include <hip/hip_bf16.h>

// ---- problem constants ----
#define NW 5
#define KS 5
#define SEQ 196
#define DIM 384
#define NSUP 25        // NW*KS support images
#define NQRY 75        // query images
#define NIMG 100       // NSUP + NQRY
#define LSUP 4900      // NSUP*SEQ support rows
#define LSUP_PAD 4992  // 39*128, zero-padded K rows
#define QROWS 208      // padded qs rows per image (13*16)
#define BLOCK_W 980    // KS*SEQ rows per class block
#define OPT_STEPS 15
#define MTILES 39      // LSUP_PAD / MT
#define NSUPWG (NSUP * MTILES)   // 975 support GEMM blocks
#define NQWG   (NQRY * MTILES)   // 2925 query GEMM blocks
#define NORMWG ((LSUP_PAD + NIMG * QROWS) / 4)   // 6448 norm blocks
#define SPIN_LIMIT (1u << 22)    // hang-proofing

static constexpr float TEMP_F = 0.0510310363f;
static constexpr float INV_T  = 1.0f / TEMP_F;   // ~19.5959
static constexpr float LR_F   = 0.1f;

typedef short v8s __attribute__((ext_vector_type(8)));   // 8 x bf16 frag (4 VGPRs)
typedef float v4f __attribute__((ext_vector_type(4)));   // 4 x f32 acc

__device__ inline unsigned short f2bf(float x) {
    unsigned int u = __float_as_uint(x);
    u += 0x7fffu + ((u >> 16) & 1u);
    return (unsigned short)(u >> 16);
}

// agent-scope ops execute at the fabric coherence point (cross-XCD correct).
// RMW reads (fetch_add 0) are guaranteed-fresh there.
__device__ __forceinline__ float fresh_f32(float* p) {
    return __hip_atomic_fetch_add(p, 0.0f, __ATOMIC_RELAXED, __HIP_MEMORY_SCOPE_AGENT);
}
__device__ __forceinline__ unsigned fresh_u32(unsigned* p) {
    return __hip_atomic_fetch_add(p, 0u, __ATOMIC_RELAXED, __HIP_MEMORY_SCOPE_AGENT);
}
__device__ __forceinline__ void agent_store_f32(float* p, float v) {
    __hip_atomic_store(p, v, __ATOMIC_RELAXED, __HIP_MEMORY_SCOPE_AGENT);
}

// ---------------------------------------------------------------------------
// Kernel 1: fused normalize. Wave-per-row. Block NORMWG zeroes Dbuf/sdone
// (replaces hipMemsetAsync dispatches).
// ---------------------------------------------------------------------------
__global__ __launch_bounds__(256) void norm_all(const float* __restrict__ supk,
                                                const float* __restrict__ supq,
                                                const float* __restrict__ qry,
                                                unsigned short* __restrict__ Kb,
                                                unsigned short* __restrict__ Qall,
                                                float* __restrict__ zbuf) {
    if (blockIdx.x == NORMWG) {
        for (int i = threadIdx.x; i < (OPT_STEPS + 1) * 125 + 64; i += 256)
            zbuf[i] = 0.f;
        return;
    }
    int R = blockIdx.x * 4 + (threadIdx.x >> 6);
    int l = threadIdx.x & 63;
    unsigned short* out;
    const float* in;
    float scale;
    if (R < LSUP_PAD) {
        out = Kb + (size_t)R * DIM;
        if (R >= LSUP) {
            #pragma unroll
            for (int k = 0; k < 6; ++k) out[l + 64 * k] = 0;
            return;
        }
        in = supk + (size_t)R * DIM;
        scale = INV_T;
    } else {
        int i = R - LSUP_PAD;
        int img = i / QROWS;
        int r = i - img * QROWS;
        out = Qall + (size_t)i * DIM;
        if (r >= SEQ) {
            #pragma unroll
            for (int k = 0; k < 6; ++k) out[l + 64 * k] = 0;
            return;
        }
        in = (img < NSUP)
            ? supq + ((size_t)img * SEQ + r) * DIM
            : qry  + ((size_t)(img - NSUP) * SEQ + r) * DIM;
        scale = 1.0f;
    }
    float x[6];
    #pragma unroll
    for (int k = 0; k < 6; ++k) x[k] = in[l + 64 * k];
    float s = 0.f;
    #pragma unroll
    for (int k = 0; k < 6; ++k) s += x[k] * x[k];
    #pragma unroll
    for (int m = 1; m < 64; m <<= 1) s += __shfl_xor(s, m);
    float sc = scale / fmaxf(sqrtf(s), 1e-8f);
    #pragma unroll
    for (int k = 0; k < 6; ++k) out[l + 64 * k] = f2bf(x[k] * sc);
}

// ---------------------------------------------------------------------------
// GEMM body: round-6 proven structure (mega=145us). KCC=64, single-buffered,
// 2 barriers per K-step, 128B-per-row line-aligned global_load_lds, XOR
// swizzle slot' = slot ^ (row&7) (rule #21), bijective XCD remap.
// SUPPORT blocks additionally: (a) write R via agent-scope (sc1) stores so
// co-resident opt blocks can read; (b) LDS-reduce their rows' exp-sums per
// class segment and atomicAdd into D0 = Dbuf[0] (opt skips the step-0
// exchange — D0 readiness coincides with sdone); (c) bump sdone.
// QUERY blocks: plain fp32 stores (round-9 lesson: sc1 for 2925 blocks ~2x).
// D0 layout: D0[w*25 + b] (per-producer-contiguous, matches Dbuf steps).
// ---------------------------------------------------------------------------
#define MT  128
#define NTP 208
#define KCC 64

__device__ __forceinline__ void gload16(const void* g, void* l) {
    __builtin_amdgcn_global_load_lds(
        (__attribute__((address_space(1))) void*)g,
        (__attribute__((address_space(3))) void*)l, 16, 0, 0);
}

template<int IMG_BASE, int NWG, bool SUPPORT>
__device__ __forceinline__ void gemm_body(
    int gid,
    const unsigned short* __restrict__ Kb,     // [4992][384] bf16, pre /T
    const unsigned short* __restrict__ Qall,   // [100][208][384] bf16
    float* __restrict__ Rall,
    float* __restrict__ D0,                    // Dbuf step-0 block [5][25]
    unsigned* counter,
    unsigned short* Asm, unsigned short* Bsm)
{
    int t = threadIdx.x;

    // bijective XCD-aware remap (m204)
    constexpr int qq = NWG >> 3;
    constexpr int rr = NWG & 7;
    int xcd = gid & 7;
    int sub = gid >> 3;
    int L = (xcd < rr ? xcd * (qq + 1) : rr * (qq + 1) + (xcd - rr) * qq) + sub;
    int img = IMG_BASE + L / MTILES;
    int m_base = (L % MTILES) * MT;

    const unsigned short* Qimg = Qall + (size_t)img * (QROWS * DIM);

    int wv = t >> 6;        // wave 0..3
    int l  = t & 63;
    int lo = l & 15;        // MFMA frag row/col index
    int hi = l >> 4;        // k-group
    int mh = (wv >> 1) * 64;   // M-half base row
    int nh = wv & 1;           // N-half

    int srow = l >> 3;
    int skp  = (l & 7) ^ srow;      // involution within 8-slot row
    const unsigned short* aSrc = Kb   + (size_t)(m_base + wv * 32 + srow) * DIM + skp * 8;
    const unsigned short* bSrc = Qimg + (size_t)srow * DIM + skp * 8;

    v4f acc[4][7];
    #pragma unroll
    for (int m = 0; m < 4; ++m)
        #pragma unroll
        for (int n = 0; n < 7; ++n)
            acc[m][n] = (v4f){0.f, 0.f, 0.f, 0.f};

    for (int kb = 0; kb < DIM; kb += KCC) {
        #pragma unroll
        for (int j = 0; j < 4; ++j)
            gload16(aSrc + (size_t)j * 8 * DIM + kb,
                    Asm + (wv * 32 + j * 8) * KCC);
        #pragma unroll
        for (int jj = 0; jj < 7; ++jj) {
            int j = wv + jj * 4;
            if (j < 26)
                gload16(bSrc + (size_t)j * 8 * DIM + kb,
                        Bsm + j * 8 * KCC);
        }
        __syncthreads();   // drains vmcnt before LDS reads

        const unsigned short* Ar = Asm + (mh + lo) * KCC;
        const unsigned short* Br = Bsm + (nh * 112 + lo) * KCC;
        #pragma unroll
        for (int kk = 0; kk < 2; ++kk) {
            int koff = ((hi + 4 * kk) ^ (lo & 7)) * 8;   // swizzled k-slot
            v8s a0 = *(const v8s*)(Ar + koff);
            v8s a1 = *(const v8s*)(Ar + 16 * KCC + koff);
            v8s a2 = *(const v8s*)(Ar + 32 * KCC + koff);
            v8s a3 = *(const v8s*)(Ar + 48 * KCC + koff);
            #pragma unroll
            for (int n = 0; n < 7; ++n) {
                if (nh == 0 || n < 6) {   // wave-uniform
                    v8s bb = *(const v8s*)(Br + n * 16 * KCC + koff);
                    acc[0][n] = __builtin_amdgcn_mfma_f32_16x16x32_bf16(a0, bb, acc[0][n], 0, 0, 0);
                    acc[1][n] = __builtin_amdgcn_mfma_f32_16x16x32_bf16(a1, bb, acc[1][n], 0, 0, 0);
                    acc[2][n] = __builtin_amdgcn_mfma_f32_16x16x32_bf16(a2, bb, acc[2][n], 0, 0, 0);
                    acc[3][n] = __builtin_amdgcn_mfma_f32_16x16x32_bf16(a3, bb, acc[3][n], 0, 0, 0);
                }
            }
        }
        __syncthreads();
    }

    // epilogue: exp + per-wave column-half sums. C/D: col=lo, row=hi*4+reg.
    float s[4][4];
    #pragma unroll
    for (int m = 0; m < 4; ++m)
        #pragma unroll
        for (int j = 0; j < 4; ++j) s[m][j] = 0.f;
    #pragma unroll
    for (int n = 0; n < 7; ++n) {
        if (nh == 0 || n < 6) {
            bool ok = ((nh * 7 + n) * 16 + lo) < SEQ;
            #pragma unroll
            for (int m = 0; m < 4; ++m)
                #pragma unroll
                for (int j = 0; j < 4; ++j)
                    s[m][j] += ok ? __expf(acc[m][n][j]) : 0.f;
        }
    }
    #pragma unroll
    for (int mm = 1; mm < 16; mm <<= 1) {
        #pragma unroll
        for (int m = 0; m < 4; ++m)
            #pragma unroll
            for (int j = 0; j < 4; ++j)
                s[m][j] += __shfl_xor(s[m][j], mm);
    }
    float* rp = (float*)Asm;   // reuse A LDS: [2][128] row partials
    if (lo == 0) {
        #pragma unroll
        for (int m = 0; m < 4; ++m)
            #pragma unroll
            for (int j = 0; j < 4; ++j)
                rp[nh * 128 + mh + m * 16 + hi * 4 + j] = s[m][j];
    }
    if (SUPPORT && t == 0) { rp[256] = 0.f; rp[257] = 0.f; }  // D0 partials
    __syncthreads();
    int w0 = m_base / BLOCK_W;
    if (t < MT) {
        int gr = m_base + t;
        if (gr < LSUP) {
            float o = rp[t] + rp[128 + t];
            if (img < NSUP && (gr / SEQ) == img) o = 0.f;
            if (SUPPORT) {   // write-through so co-resident opt blocks see it
                agent_store_f32(&Rall[(size_t)img * LSUP + gr], o);
                atomicAdd(&rp[256 + (gr / BLOCK_W - w0)], o);  // LDS atomic
            } else {
                Rall[(size_t)img * LSUP + gr] = o;
            }
        }
    }
    if (SUPPORT) {
        __syncthreads();   // LDS D0 partials complete
        if (t < 2) {
            int w = w0 + t;
            if (w < NW && w * BLOCK_W < m_base + MT)   // class intersects tile
                atomicAdd(&D0[w * NSUP + img], rp[256 + t]);  // device-scope
        }
        __syncthreads();   // vmcnt(0): sc1 stores + atomics acked
        if (t == 0)
            __hip_atomic_fetch_add(counter, 1u, __ATOMIC_RELAXED, __HIP_MEMORY_SCOPE_AGENT);
    }
}

// ---------------------------------------------------------------------------
// Kernel 2: MEGA kernel, 3905 blocks x 256 (round-6 structure).
// ids 0..4: optimizer (class w = id). ids 5..979: support GEMM.
// ids 980..3904: query GEMM.
// Exchange (round-15 change): PAYLOAD-AS-FLAG. Dbuf[step][w][b] is
// per-producer contiguous (2 cache lines per producer); producer does 25
// agent stores, NO flag, NO drain barrier. Consumers poll the 100 remote
// payload words directly with independent RMWs + s_sleep backoff (values
// provably > 0; buffers pre-zeroed). Own-class read from LDS. This
// collapses the serialized store->flag->poll->read chain (~3 RTT) to ~1 RTT.
// D0 comes from support-block atomics (readiness == sdone). Spins bounded.
// ---------------------------------------------------------------------------
__global__ __launch_bounds__(256, 3) void mega(
    const unsigned short* __restrict__ Kb,
    const unsigned short* __restrict__ Qall,
    float* __restrict__ Rall,
    const int* __restrict__ labels,
    float* __restrict__ Dbufs,      // [16][5][25], pre-zeroed (norm_all)
    unsigned* __restrict__ sdone,   // support-done counter, pre-zeroed
    float* __restrict__ e_out)      // [4900] final e^{v/T}
{
    __shared__ __align__(16) unsigned short Asm[MT * KCC];    // 16 KiB
    __shared__ __align__(16) unsigned short Bsm[NTP * KCC];   // 26 KiB

    int id = blockIdx.x;
    if (id >= NW + NSUPWG) {
        gemm_body<NSUP, NQWG, false>(id - (NW + NSUPWG), Kb, Qall, Rall,
                                     Dbufs, sdone, Asm, Bsm);
        return;
    }
    if (id >= NW) {
        gemm_body<0, NSUPWG, true>(id - NW, Kb, Qall, Rall,
                                   Dbufs, sdone, Asm, Bsm);
        return;
    }

    // ---- optimizer block for class w ----
    float* sh  = (float*)Asm;
    float* red = sh;              // [4][25]
    float* cfs = sh + 100;        // [25]
    float* Dsm = sh + 128;        // [125]
    float* myD = sh + 256;        // [25]
    int*   lsm = (int*)(sh + 288);// [25]

    int w = id;
    int t = threadIdx.x;
    int wave = t >> 6, lane = t & 63;

    // wait for all 975 support blocks (R and D0 both ready at this point)
    if (t == 0) {
        unsigned spins = 0;
        while (fresh_u32(sdone) < (unsigned)NSUPWG && ++spins < SPIN_LIMIT)
            __builtin_amdgcn_s_sleep(8);
    }
    __syncthreads();

    // rows r = t + 256k, k<4 (k=3 valid only for t<212); inactive rows -> 0.
    float Rv[4][NSUP];
    #pragma unroll
    for (int b = 0; b < NSUP; ++b) {
        const float* Rb = Rall + (size_t)b * LSUP + w * BLOCK_W;
        Rv[0][b] = Rb[t];
        Rv[1][b] = Rb[t + 256];
        Rv[2][b] = Rb[t + 512];
        Rv[3][b] = (t < BLOCK_W - 768) ? Rb[t + 768] : 0.f;
    }
    if (t < NSUP) lsm[t] = labels[t];

    float e0 = 1.f, e1 = 1.f, e2 = 1.f, e3 = 1.f;
    float v0 = 0.f, v1 = 0.f, v2 = 0.f, v3 = 0.f;

    auto pushD = [&](int step) {
        float part[NSUP];
        #pragma unroll
        for (int b = 0; b < NSUP; ++b)
            part[b] = e0 * Rv[0][b] + e1 * Rv[1][b] + e2 * Rv[2][b] + e3 * Rv[3][b];
        #pragma unroll
        for (int b = 0; b < NSUP; ++b) {
            #pragma unroll
            for (int m = 32; m; m >>= 1) part[b] += __shfl_xor(part[b], m);
        }
        if (lane == 0) {
            #pragma unroll
            for (int b = 0; b < NSUP; ++b) red[wave * NSUP + b] = part[b];
        }
        __syncthreads();
        if (t < NSUP) {
            float s2 = red[t] + red[NSUP + t] + red[2 * NSUP + t] + red[3 * NSUP + t];
            myD[t] = s2;                                   // LDS self-copy
            agent_store_f32(&Dbufs[step * 125 + w * NSUP + t], s2);
        }
        // no drain barrier, no flag: payload IS the flag (values > 0)
    };

    for (int s = 0; s < OPT_STEPS; ++s) {
        if (t < 125) {
            int wp = t / 25, b = t - wp * 25;
            float dv;
            if (s > 0 && wp == w) {
                dv = myD[b];
            } else if (s == 0) {
                dv = fresh_f32(&Dbufs[wp * NSUP + b]);     // complete at sdone
            } else {
                unsigned spins = 0;
                for (;;) {
                    dv = fresh_f32(&Dbufs[s * 125 + wp * NSUP + b]);
                    if (dv != 0.f || ++spins >= SPIN_LIMIT) break;
                    __builtin_amdgcn_s_sleep(2);
                }
            }
            Dsm[b * 5 + wp] = dv;
        }
        __syncthreads();
        if (t < NSUP) {
            float Dsum = 0.f, Dw = 1.f;
            #pragma unroll
            for (int ww = 0; ww < NW; ++ww) {
                float d = Dsm[t * 5 + ww];
                Dsum += d;
                if (ww == w) Dw = d;
            }
            cfs[t] = ((Dw / Dsum) - (w == lsm[t] ? 1.f : 0.f)) * (INV_T / 25.f) / Dw;
        }
        __syncthreads();
        float g0 = 0.f, g1 = 0.f, g2 = 0.f, g3 = 0.f;
        #pragma unroll
        for (int b = 0; b < NSUP; ++b) {
            float c = cfs[b];
            g0 += c * Rv[0][b];
            g1 += c * Rv[1][b];
            g2 += c * Rv[2][b];
            g3 += c * Rv[3][b];
        }
        v0 -= LR_F * e0 * g0; e0 = __expf(v0 * INV_T);
        v1 -= LR_F * e1 * g1; e1 = __expf(v1 * INV_T);
        v2 -= LR_F * e2 * g2; e2 = __expf(v2 * INV_T);
        v3 -= LR_F * e3 * g3; e3 = __expf(v3 * INV_T);
        __syncthreads();      // red/Dsm/cfs reuse protection
        if (s + 1 < OPT_STEPS) {
            pushD(s + 1);
            __syncthreads();  // myD visible before next fill phase
        }
    }

    // export e (plain stores; kernel-end writeback covers final_pred)
    float* eo = e_out + w * BLOCK_W;
    eo[t]       = e0;
    eo[t + 256] = e1;
    eo[t + 512] = e2;
    if (t < BLOCK_W - 768) eo[t + 768] = e3;
}

// ---------------------------------------------------------------------------
// Kernel 3: final prediction. 375 blocks (qb*5+w) x 256.
// ---------------------------------------------------------------------------
__global__ __launch_bounds__(256) void final_pred(const float* __restrict__ Rall,
                                                  const float* __restrict__ e_out,
                                                  float* __restrict__ out) {
    __shared__ float ws[4];
    int blk = blockIdx.x;
    int qb = blk / 5, w = blk % 5;
    const float* R  = Rall + (size_t)(NSUP + qb) * LSUP + w * BLOCK_W;
    const float* eb = e_out + w * BLOCK_W;
    int t = threadIdx.x;
    float p = 0.f;
    for (int i = t; i < BLOCK_W; i += 256) p += eb[i] * R[i];
    #pragma unroll
    for (int m = 32; m; m >>= 1) p += __shfl_xor(p, m);
    if ((t & 63) == 0) ws[t >> 6] = p;
    __syncthreads();
    if (t == 0) out[blk] = logf(ws[0] + ws[1] + ws[2] + ws[3]);
}

// ---------------------------------------------------------------------------
extern "C" void kernel_launch(void* const* d_in, const int* in_sizes, int n_in,
                              void* d_out, int out_size, void* d_ws, size_t ws_size,
                              hipStream_t stream) {
    const float* sup_key = (const float*)d_in[0];   // [25,196,384]
    const float* sup_qry = (const float*)d_in[1];   // [25,196,384]
    const float* qry     = (const float*)d_in[2];   // [75,196,384]
    const int*   labels  = (const int*)d_in[3];     // [25]
    float* out = (float*)d_out;                     // [75,5]

    char* ws = (char*)d_ws;
    size_t off = 0;
    auto take = [&](size_t bytes) {
        char* p = ws + off;
        off = (off + bytes + 255) & ~(size_t)255;
        return p;
    };
    unsigned short* Kb   = (unsigned short*)take((size_t)LSUP_PAD * DIM * 2);
    unsigned short* Qall = (unsigned short*)take((size_t)NIMG * QROWS * DIM * 2);
    float*          Rall = (float*)take((size_t)NIMG * LSUP * 4);
    float*          Dbuf = (float*)take(((size_t)(OPT_STEPS + 1) * 125 + 64) * 4);
    float*          eout = (float*)take((size_t)LSUP * 4);
    unsigned*       sdone = (unsigned*)(Dbuf + (OPT_STEPS + 1) * 125);

    norm_all<<<NORMWG + 1, 256, 0, stream>>>(
        sup_key, sup_qry, qry, Kb, Qall, Dbuf);

    mega<<<NW + NSUPWG + NQWG, 256, 0, stream>>>(
        Kb, Qall, Rall, labels, Dbuf, sdone, eout);

    final_pred<<<NQRY * NW, 256, 0, stream>>>(Rall, eout, out);
}